// Round 7
// baseline (75.556 us; speedup 1.0000x reference)
//
#include <hip/hip_runtime.h>

// d_ws layout: 8 gates (layer*4+q) x 8 floats {m00r,m00i,m01r,m01i,m10r,m10i,m11r,m11i}
// where M = RZ(tz) * RY(ty) (RY applied first), ty=angles[l][q][0]/2, tz=angles[l][q][1]/2.
static __global__ void prep_consts(const float* __restrict__ angles,
                                   float* __restrict__ cst) {
    int g = threadIdx.x;
    if (g < 8) {
        int layer = g >> 2, q = g & 3;
        float ty = angles[(layer * 4 + q) * 2 + 0] * 0.5f;
        float tz = angles[(layer * 4 + q) * 2 + 1] * 0.5f;
        float cy, sy, cz, sz;
        sincosf(ty, &sy, &cy);   // precise trig; runs once on 8 threads, cost irrelevant
        sincosf(tz, &sz, &cz);
        float* m = cst + g * 8;
        m[0] = cy * cz;  m[1] = -cy * sz;   // m00 = cy * e^{-i tz}
        m[2] = -sy * cz; m[3] = sy * sz;    // m01 = -sy * e^{-i tz}
        m[4] = sy * cz;  m[5] = sy * sz;    // m10 = sy * e^{+i tz}
        m[6] = cy * cz;  m[7] = cy * sz;    // m11 = cy * e^{+i tz}
    }
}

// CNOT(control mask CM, target mask TM): for control-bit=1 amplitudes, swap across target bit.
template <int CM, int TM>
static __device__ __forceinline__ void cnot16(float (&ar)[16], float (&ai)[16]) {
#pragma unroll
    for (int i = 0; i < 16; ++i) {
        if ((i & CM) && !(i & TM)) {
            const int j = i | TM;
            float tr = ar[i]; ar[i] = ar[j]; ar[j] = tr;
            float ti = ai[i]; ai[i] = ai[j]; ai[j] = ti;
        }
    }
}

// General complex 2x2 gate on qubit with bitmask TM.
template <int TM>
static __device__ __forceinline__ void gate16(float (&ar)[16], float (&ai)[16],
                                              float m0, float m1, float m2, float m3,
                                              float m4, float m5, float m6, float m7) {
#pragma unroll
    for (int i = 0; i < 16; ++i) {
        if (!(i & TM)) {
            const int j = i | TM;
            const float a0r = ar[i], a0i = ai[i];
            const float a1r = ar[j], a1i = ai[j];
            ar[i] = m0 * a0r - m1 * a0i + m2 * a1r - m3 * a1i;
            ai[i] = m0 * a0i + m1 * a0r + m2 * a1i + m3 * a1r;
            ar[j] = m4 * a0r - m5 * a0i + m6 * a1r - m7 * a1i;
            ai[j] = m4 * a0i + m5 * a0r + m6 * a1i + m7 * a1r;
        }
    }
}

__launch_bounds__(256)
static __global__ void qsim4(const float4* __restrict__ in,
                             const float* __restrict__ cst,
                             float4* __restrict__ out, int B) {
    const int b = blockIdx.x * 256 + threadIdx.x;
    if (b >= B) return;

    const float4 x = in[b];
    float c[4], s[4];
    __sincosf(x.x * 0.5f, &s[0], &c[0]);
    __sincosf(x.y * 0.5f, &s[1], &c[1]);
    __sincosf(x.z * 0.5f, &s[2], &c[2]);
    __sincosf(x.w * 0.5f, &s[3], &c[3]);

    // Per-qubit 2-vector v = M_layer0 * (RX|0>) where RX|0> = [cos, -i sin].
    float vr[4][2], vi[4][2];
#pragma unroll
    for (int q = 0; q < 4; ++q) {
        const float m0 = cst[q * 8 + 0], m1 = cst[q * 8 + 1];
        const float m2 = cst[q * 8 + 2], m3 = cst[q * 8 + 3];
        const float m4 = cst[q * 8 + 4], m5 = cst[q * 8 + 5];
        const float m6 = cst[q * 8 + 6], m7 = cst[q * 8 + 7];
        // v0 = m00*c + m01*(-i s);  v1 = m10*c + m11*(-i s)
        vr[q][0] = m0 * c[q] + m3 * s[q];
        vi[q][0] = m1 * c[q] - m2 * s[q];
        vr[q][1] = m4 * c[q] + m7 * s[q];
        vi[q][1] = m5 * c[q] - m6 * s[q];
    }

    // Tensor product: amp[i] = v0[b0]*v1[b1]*v2[b2]*v3[b3], i = b0b1b2b3 (q0 = MSB).
    float w01r[4], w01i[4], w23r[4], w23i[4];
#pragma unroll
    for (int j = 0; j < 4; ++j) {
        const int h = j >> 1, l = j & 1;
        w01r[j] = vr[0][h] * vr[1][l] - vi[0][h] * vi[1][l];
        w01i[j] = vr[0][h] * vi[1][l] + vi[0][h] * vr[1][l];
        w23r[j] = vr[2][h] * vr[3][l] - vi[2][h] * vi[3][l];
        w23i[j] = vr[2][h] * vi[3][l] + vi[2][h] * vr[3][l];
    }
    float ar[16], ai[16];
#pragma unroll
    for (int i = 0; i < 16; ++i) {
        const int h = i >> 2, l = i & 3;
        ar[i] = w01r[h] * w23r[l] - w01i[h] * w23i[l];
        ai[i] = w01r[h] * w23i[l] + w01i[h] * w23r[l];
    }

    // Layer 0 CNOT chain: (0,1),(1,2),(2,3),(3,0). Qubit q mask = 8>>q.
    cnot16<8, 4>(ar, ai);
    cnot16<4, 2>(ar, ai);
    cnot16<2, 1>(ar, ai);
    cnot16<1, 8>(ar, ai);

    // Layer 1: combined RZ*RY gate per qubit, then CNOT chain.
#pragma unroll
    for (int q = 0; q < 4; ++q) {
        const float* m = cst + (4 + q) * 8;
        const float m0 = m[0], m1 = m[1], m2 = m[2], m3 = m[3];
        const float m4 = m[4], m5 = m[5], m6 = m[6], m7 = m[7];
        if (q == 0) gate16<8>(ar, ai, m0, m1, m2, m3, m4, m5, m6, m7);
        if (q == 1) gate16<4>(ar, ai, m0, m1, m2, m3, m4, m5, m6, m7);
        if (q == 2) gate16<2>(ar, ai, m0, m1, m2, m3, m4, m5, m6, m7);
        if (q == 3) gate16<1>(ar, ai, m0, m1, m2, m3, m4, m5, m6, m7);
    }
    cnot16<8, 4>(ar, ai);
    cnot16<4, 2>(ar, ai);
    cnot16<2, 1>(ar, ai);
    cnot16<1, 8>(ar, ai);

    // <Z_q> = sum_i (1 - 2*bit_q(i)) * |amp_i|^2, bit_q(i) = (i >> (3-q)) & 1.
    float p[16];
#pragma unroll
    for (int i = 0; i < 16; ++i) p[i] = ar[i] * ar[i] + ai[i] * ai[i];

    float e0 = 0.f, e1 = 0.f, e2 = 0.f, e3 = 0.f;
#pragma unroll
    for (int i = 0; i < 16; ++i) {
        e0 += (i & 8) ? -p[i] : p[i];
        e1 += (i & 4) ? -p[i] : p[i];
        e2 += (i & 2) ? -p[i] : p[i];
        e3 += (i & 1) ? -p[i] : p[i];
    }

    out[b] = make_float4(e0, e1, e2, e3);
}

extern "C" void kernel_launch(void* const* d_in, const int* in_sizes, int n_in,
                              void* d_out, int out_size, void* d_ws, size_t ws_size,
                              hipStream_t stream) {
    const float* inputs = (const float*)d_in[0];   // [B,4] f32
    const float* angles = (const float*)d_in[1];   // [2,4,2] f32
    float* cst = (float*)d_ws;                     // 64 floats
    const int B = in_sizes[0] / 4;

    prep_consts<<<1, 64, 0, stream>>>(angles, cst);
    qsim4<<<(B + 255) / 256, 256, 0, stream>>>((const float4*)inputs, cst,
                                               (float4*)d_out, B);
}

// Round 9
// 65.976 us; speedup vs baseline: 1.1452x; 1.1452x over previous
//
#include <hip/hip_runtime.h>

// Single fused kernel: one thread = one batch element (16 complex amps in regs).
// Batch-uniform angle trig is recomputed per-thread (~12 sincos, cheaper than a
// serialized prep launch). Layer-1 RZ gates are dropped: only CNOTs (basis
// permutations) separate them from |amp|^2, so their unit phases cancel.
// Bit convention (from reference axes [B,q0,q1,q2,q3]): qubit q <-> mask 8>>q.

// CNOT(control mask CM, target mask TM): swap across target bit where control=1.
template <int CM, int TM>
static __device__ __forceinline__ void cnot16(float (&ar)[16], float (&ai)[16]) {
#pragma unroll
    for (int i = 0; i < 16; ++i) {
        if ((i & CM) && !(i & TM)) {
            const int j = i | TM;
            float tr = ar[i]; ar[i] = ar[j]; ar[j] = tr;
            float ti = ai[i]; ai[i] = ai[j]; ai[j] = ti;
        }
    }
}

// Real RY rotation on qubit with bitmask TM: [a_i; a_j] <- [[cy,-sy],[sy,cy]] ..
template <int TM>
static __device__ __forceinline__ void ry16(float (&ar)[16], float (&ai)[16],
                                            float cy, float sy) {
#pragma unroll
    for (int i = 0; i < 16; ++i) {
        if (!(i & TM)) {
            const int j = i | TM;
            const float a0r = ar[i], a0i = ai[i];
            const float a1r = ar[j], a1i = ai[j];
            ar[i] = cy * a0r - sy * a1r;
            ai[i] = cy * a0i - sy * a1i;
            ar[j] = sy * a0r + cy * a1r;
            ai[j] = sy * a0i + cy * a1i;
        }
    }
}

__launch_bounds__(256)
static __global__ void qsim4(const float4* __restrict__ in,
                             const float* __restrict__ ang,  // [2,4,2] f32
                             float4* __restrict__ out, int B) {
    const int b = blockIdx.x * 256 + threadIdx.x;
    if (b >= B) return;

    // ---- batch-uniform trig (angles are uniform -> scalar loads) ----
    float c0y[4], s0y[4], c0z[4], s0z[4], c1y[4], s1y[4];
#pragma unroll
    for (int q = 0; q < 4; ++q) {
        __sincosf(ang[q * 2 + 0] * 0.5f, &s0y[q], &c0y[q]);       // layer0 RY
        __sincosf(ang[q * 2 + 1] * 0.5f, &s0z[q], &c0z[q]);       // layer0 RZ
        __sincosf(ang[8 + q * 2 + 0] * 0.5f, &s1y[q], &c1y[q]);   // layer1 RY (RZ dropped)
    }

    // ---- per-batch RX embedding ----
    const float4 x = in[b];
    float cx[4], sx[4];
    __sincosf(x.x * 0.5f, &sx[0], &cx[0]);
    __sincosf(x.y * 0.5f, &sx[1], &cx[1]);
    __sincosf(x.z * 0.5f, &sx[2], &cx[2]);
    __sincosf(x.w * 0.5f, &sx[3], &cx[3]);

    // Per-qubit 2-vector v = RZ0*RY0*RX|0>.
    // u = RX|0> = [cx, -i sx]; t = RY u: t0 = cx*cy + i sy*sx, t1 = sy*cx - i cy*sx
    // v0 = t0 * e^{-i tz}; v1 = t1 * e^{+i tz}
    float vr[4][2], vi[4][2];
#pragma unroll
    for (int q = 0; q < 4; ++q) {
        const float t0r = c0y[q] * cx[q], t0i = s0y[q] * sx[q];
        const float t1r = s0y[q] * cx[q], t1i = -c0y[q] * sx[q];
        vr[q][0] = t0r * c0z[q] + t0i * s0z[q];
        vi[q][0] = t0i * c0z[q] - t0r * s0z[q];
        vr[q][1] = t1r * c0z[q] - t1i * s0z[q];
        vi[q][1] = t1i * c0z[q] + t1r * s0z[q];
    }

    // Tensor product: amp[i] = v0[b0]*v1[b1]*v2[b2]*v3[b3], i = b0b1b2b3 (q0 = MSB).
    float w01r[4], w01i[4], w23r[4], w23i[4];
#pragma unroll
    for (int j = 0; j < 4; ++j) {
        const int h = j >> 1, l = j & 1;
        w01r[j] = vr[0][h] * vr[1][l] - vi[0][h] * vi[1][l];
        w01i[j] = vr[0][h] * vi[1][l] + vi[0][h] * vr[1][l];
        w23r[j] = vr[2][h] * vr[3][l] - vi[2][h] * vi[3][l];
        w23i[j] = vr[2][h] * vi[3][l] + vi[2][h] * vr[3][l];
    }
    float ar[16], ai[16];
#pragma unroll
    for (int i = 0; i < 16; ++i) {
        const int h = i >> 2, l = i & 3;
        ar[i] = w01r[h] * w23r[l] - w01i[h] * w23i[l];
        ai[i] = w01r[h] * w23i[l] + w01i[h] * w23r[l];
    }

    // Layer 0 CNOT chain: (0,1),(1,2),(2,3),(3,0) -> masks (8,4),(4,2),(2,1),(1,8).
    cnot16<8, 4>(ar, ai);
    cnot16<4, 2>(ar, ai);
    cnot16<2, 1>(ar, ai);
    cnot16<1, 8>(ar, ai);

    // Layer 1: RY per qubit (RZ phases cancel under the following permutations+abs2).
    ry16<8>(ar, ai, c1y[0], s1y[0]);
    ry16<4>(ar, ai, c1y[1], s1y[1]);
    ry16<2>(ar, ai, c1y[2], s1y[2]);
    ry16<1>(ar, ai, c1y[3], s1y[3]);
    cnot16<8, 4>(ar, ai);
    cnot16<4, 2>(ar, ai);
    cnot16<2, 1>(ar, ai);
    cnot16<1, 8>(ar, ai);

    // probs and factorized Z-expectations.
    float p[16];
#pragma unroll
    for (int i = 0; i < 16; ++i) p[i] = ar[i] * ar[i] + ai[i] * ai[i];

    float p2[8], p4[4], p8[2];
#pragma unroll
    for (int j = 0; j < 8; ++j) p2[j] = p[2 * j] + p[2 * j + 1];
#pragma unroll
    for (int j = 0; j < 4; ++j) p4[j] = p2[2 * j] + p2[2 * j + 1];
    p8[0] = p4[0] + p4[1];
    p8[1] = p4[2] + p4[3];

    const float e0 = p8[0] - p8[1];
    const float e1 = (p4[0] - p4[1]) + (p4[2] - p4[3]);
    const float e2 = (p2[0] - p2[1]) + (p2[2] - p2[3]) + (p2[4] - p2[5]) + (p2[6] - p2[7]);
    float e3 = 0.f;
#pragma unroll
    for (int j = 0; j < 8; ++j) e3 += p[2 * j] - p[2 * j + 1];

    out[b] = make_float4(e0, e1, e2, e3);
}

extern "C" void kernel_launch(void* const* d_in, const int* in_sizes, int n_in,
                              void* d_out, int out_size, void* d_ws, size_t ws_size,
                              hipStream_t stream) {
    const float* inputs = (const float*)d_in[0];   // [B,4] f32
    const float* angles = (const float*)d_in[1];   // [2,4,2] f32
    const int B = in_sizes[0] / 4;
    (void)d_ws; (void)ws_size;

    qsim4<<<(B + 255) / 256, 256, 0, stream>>>((const float4*)inputs, angles,
                                               (float4*)d_out, B);
}